// Round 5
// baseline (172.257 us; speedup 1.0000x reference)
//
#include <hip/hip_runtime.h>
#include <hip/hip_fp16.h>
#include <cmath>

// Problem constants: (N,C,H,W) = (16,3,512,512), fp32
#define PLANE (512*512)          // 262144
#define NPLANES 48               // N*C
#define NEL (48*PLANE)           // 12582912

struct Taps { float k[9]; };
struct CMat { float w[3][3]; };   // C-axis 9-tap blur collapsed to 3x3 matrix

// ws layout (all fp16, TILED):
//   ushort index(p, h, w-slot) = ((h*8 + tile)*96 + p)*64 + slot
// Each lane owns 8 cols (col=8l..8l+7) stored as 4 uints pairing
// (col+i, col+i+4) in (lo,hi) halves. wsS and wsI use the SAME pairing and
// k_cn_loss is pairing-agnostic (order-independent mean; C/N blurs act
// per-point across planes).
//   wsS[0 .. 2*NEL)   : HW-blurred log, planes 0..47 = image E, 48..95 = G
//   wsI[0 .. 2*NEL)   : (I + 1e-6) values, same plane order

#define FOLD(r) ((r) < 0 ? (-1 - (r)) : ((r) > 511 ? (1023 - (r)) : (r)))

// ---------------------------------------------------------------------------
// Kernel 1: fused log + W-blur + H-blur + I-fp16 staging.
// ONE wave per (8-row strip x FULL 512-col row) of one plane: 8 cols/lane,
// no interior halo, no barriers. Depth-3 load pipeline. Packed (i,i+4) fp16
// W/H blur (R4-verified datapath, absmax 0.0). 8-row strips double the wave
// count vs R4: grid (64, 96) = 6144 waves = 24/CU for latency hiding.
// Block (0,0) also zeroes the loss accumulator (replaces memset dispatch).
// ---------------------------------------------------------------------------
__global__ __launch_bounds__(64)
void k_blur_hw(const float* __restrict__ inE, const float* __restrict__ inG,
               ushort* __restrict__ wsS, ushort* __restrict__ wsI,
               float* __restrict__ out, Taps tp)
{
    const int l  = threadIdx.x;               // 0..63 -> cols 8l..8l+7
    const int r0 = blockIdx.x * 8;            // 64 rowgroups
    const int z  = blockIdx.y;                // plane 0..95
    if (blockIdx.x == 0 && blockIdx.y == 0 && l == 0) *out = 0.f;  // stream-ordered before k_cn_loss
    const float* __restrict__ src = (z < NPLANES) ? (inE + z * PLANE)
                                                  : (inG + (z - NPLANES) * PLANE);
    const int col  = 8 * l;
    const int tile = l >> 3;                  // w-tile 0..7
    const int sh   = (l & 7) * 8;             // ushort offset inside tile block

    __half2 kh[9];
#pragma unroll
    for (int t = 0; t < 9; ++t) kh[t] = __float2half2_rn(tp.k[t]);

    uint ring[9][4];                          // W-blurred rows, (i,i+4) pairs

    // depth-3 load pipeline over rows r0-4+j
    float4 pA[3], pB[3];
#pragma unroll
    for (int s = 0; s < 3; ++s) {
        const int row = FOLD(r0 - 4 + s);
        pA[s] = *(const float4*)(src + row * 512 + col);
        pB[s] = *(const float4*)(src + row * 512 + col + 4);
    }

#pragma unroll
    for (int j = 0; j < 16; ++j) {            // input row r0-4+j
        const float4 a = pA[0], b = pB[0];
        pA[0] = pA[1]; pA[1] = pA[2];
        pB[0] = pB[1]; pB[1] = pB[2];
        if (j + 3 < 16) {                     // load row j+3 (3-iter slack)
            const int row = FOLD(r0 - 1 + j);
            pA[2] = *(const float4*)(src + row * 512 + col);
            pB[2] = *(const float4*)(src + row * 512 + col + 4);
        }

        const float a0 = a.x + 1e-6f, a1 = a.y + 1e-6f;
        const float a2 = a.z + 1e-6f, a3 = a.w + 1e-6f;
        const float b0 = b.x + 1e-6f, b1 = b.y + 1e-6f;
        const float b2 = b.z + 1e-6f, b3 = b.w + 1e-6f;

        // stage (I+eps) as fp16 pairs for the 8 center rows
        if (j >= 4 && j < 12) {
            const int ri = r0 + j - 4;
            __half2 i0 = __floats2half2_rn(a0, b0);
            __half2 i1 = __floats2half2_rn(a1, b1);
            __half2 i2 = __floats2half2_rn(a2, b2);
            __half2 i3 = __floats2half2_rn(a3, b3);
            ushort* dpI = wsI + (((ri * 8 + tile) * 96) + z) * 64 + sh;
            *(uint4*)dpI = make_uint4(*(uint*)&i0, *(uint*)&i1,
                                      *(uint*)&i2, *(uint*)&i3);
        }

        // fp32 log -> packed (i,i+4) fp16 pairs
        uint c[4];
        {
            __half2 h0 = __floats2half2_rn(__logf(a0), __logf(b0));
            __half2 h1 = __floats2half2_rn(__logf(a1), __logf(b1));
            __half2 h2 = __floats2half2_rn(__logf(a2), __logf(b2));
            __half2 h3 = __floats2half2_rn(__logf(a3), __logf(b3));
            c[0] = *(uint*)&h0; c[1] = *(uint*)&h1;
            c[2] = *(uint*)&h2; c[3] = *(uint*)&h3;
        }

        // 12 packed windows: wpk[x] = (w[col-4+x], w[col+x]), x=0..11
        uint wpk[12];
#pragma unroll
        for (int i = 0; i < 4; ++i) {
            const uint up = (uint)__shfl_up((int)c[i], 1);
            const uint dn = (uint)__shfl_down((int)c[i], 1);
            wpk[i]     = (up >> 16) | (c[i] << 16);   // (up.hi, own.lo)
            wpk[4 + i] = c[i];
            wpk[8 + i] = (c[i] >> 16) | (dn << 16);   // (own.hi, down.lo)
        }
        if (l == 0) {                     // reflect cols -4..-1 -> 3..0
#pragma unroll
            for (int x = 0; x < 4; ++x)
                wpk[x] = (c[3 - x] & 0xffffu) | (c[x] << 16);
        }
        if (l == 63) {                    // reflect cols 512..515 -> 511..508
            wpk[8]  = (c[0] >> 16) | (c[3] & 0xffff0000u);
            wpk[9]  = (c[1] >> 16) | (c[2] & 0xffff0000u);
            wpk[10] = (c[2] >> 16) | (c[1] & 0xffff0000u);
            wpk[11] = (c[3] >> 16) | (c[0] & 0xffff0000u);
        }

        // W-blur, packed fp16: out_pk[i] = (out[col+i], out[col+i+4])
#pragma unroll
        for (int i = 0; i < 4; ++i) {
            __half2 acc = __hmul2(kh[0], *(__half2*)&wpk[i]);
#pragma unroll
            for (int t = 1; t < 9; ++t)
                acc = __hfma2(kh[t], *(__half2*)&wpk[i + t], acc);
            ring[j % 9][i] = *(uint*)&acc;
        }

        // H-blur + store once 9 rows live (output row r0+j-8)
        if (j >= 8) {
            __half2 s0, s1, s2, s3;
            {
                const int sl = (j - 8) % 9;           // slot of row j-8
                s0 = __hmul2(kh[0], *(__half2*)&ring[sl][0]);
                s1 = __hmul2(kh[0], *(__half2*)&ring[sl][1]);
                s2 = __hmul2(kh[0], *(__half2*)&ring[sl][2]);
                s3 = __hmul2(kh[0], *(__half2*)&ring[sl][3]);
            }
#pragma unroll
            for (int t = 1; t < 9; ++t) {
                const int sl = (j - 8 + t) % 9;       // compile-time
                s0 = __hfma2(kh[t], *(__half2*)&ring[sl][0], s0);
                s1 = __hfma2(kh[t], *(__half2*)&ring[sl][1], s1);
                s2 = __hfma2(kh[t], *(__half2*)&ring[sl][2], s2);
                s3 = __hfma2(kh[t], *(__half2*)&ring[sl][3], s3);
            }
            const int ro = r0 + j - 8;
            ushort* dpS = wsS + (((ro * 8 + tile) * 96) + z) * 64 + sh;
            *(uint4*)dpS = make_uint4(*(uint*)&s0, *(uint*)&s1,
                                      *(uint*)&s2, *(uint*)&s3);
        }
    }
}

// ---------------------------------------------------------------------------
// Kernel 2: C-blur + N-blur + loss, N-SPLIT across 2 threads per point-pair.
// Half H covers n = 8H .. 8H+7 and needs only S-rows (H?4:0)..(H?15:11)
// (12 rows vs 16). 2x the waves (4096 = 16/CU), 120 loads/thread (vs 192).
// Blocks 0..511 = half 0, 512..1023 = half 1 (full 256B coalescing kept).
// grid (1024), block (256).
// ---------------------------------------------------------------------------
template <int H>
__device__ __forceinline__ float cn_half(const ushort* __restrict__ sbase,
                                         const ushort* __restrict__ ibase,
                                         const __half2 k2[9],
                                         const __half2 cw[3][3])
{
    __half2 re[9][3];   // ring of C-blurred smoothed-log(E), slot = row % 9
    __half2 rg[9][3];

#define LOADRAW(m, uE, uG)                                                     \
    uE[0] = *(const uint*)(sbase + ((m) * 3 + 0) * 64);                        \
    uE[1] = *(const uint*)(sbase + ((m) * 3 + 1) * 64);                        \
    uE[2] = *(const uint*)(sbase + ((m) * 3 + 2) * 64);                        \
    uG[0] = *(const uint*)(sbase + (48 + (m) * 3 + 0) * 64);                   \
    uG[1] = *(const uint*)(sbase + (48 + (m) * 3 + 1) * 64);                   \
    uG[2] = *(const uint*)(sbase + (48 + (m) * 3 + 2) * 64);

#define CBLUR(u, dst)                                                          \
    {                                                                          \
        __half2 v0 = *(__half2*)&u[0];                                         \
        __half2 v1 = *(__half2*)&u[1];                                         \
        __half2 v2 = *(__half2*)&u[2];                                         \
        dst[0] = __hfma2(cw[0][0], v0, __hfma2(cw[0][1], v1, __hmul2(cw[0][2], v2))); \
        dst[1] = __hfma2(cw[1][0], v0, __hfma2(cw[1][1], v1, __hmul2(cw[1][2], v2))); \
        dst[2] = __hfma2(cw[2][0], v0, __hfma2(cw[2][1], v1, __hmul2(cw[2][2], v2))); \
    }

    // prime rows (H?4:0) .. 8H+3
#pragma unroll
    for (int m = (H ? 4 : 0); m < 8 * H + 4; ++m) {
        uint uE[3], uG[3];
        LOADRAW(m, uE, uG);
        CBLUR(uE, re[m % 9]); CBLUR(uG, rg[m % 9]);
    }

    float acc = 0.f;
#pragma unroll
    for (int n = 8 * H; n < 8 * H + 8; ++n) {
        // new S-row n+4 (if within this half's folded range)
        if (n + 4 <= (H ? 15 : 11)) {
            uint uE[3], uG[3];
            LOADRAW(n + 4, uE, uG);
            CBLUR(uE, re[(n + 4) % 9]); CBLUR(uG, rg[(n + 4) % 9]);
        }
        // (I+eps) pairs for row n
        uint ieq[3], igq[3];
#pragma unroll
        for (int c = 0; c < 3; ++c) {
            ieq[c] = *(const uint*)(ibase + (n * 3 + c) * 64);
            igq[c] = *(const uint*)(ibase + ((48 + n * 3 + c)) * 64);
        }
#pragma unroll
        for (int c = 0; c < 3; ++c) {
            __half2 se2 = __float2half2_rn(0.f), sg2 = se2;
#pragma unroll
            for (int t = 0; t < 9; ++t) {
                int m = n - 4 + t;
                m = (m < 0) ? (-1 - m) : ((m > 15) ? (31 - m) : m);  // compile-time
                se2 = __hfma2(k2[t], re[m % 9][c], se2);
                sg2 = __hfma2(k2[t], rg[m % 9][c], sg2);
            }
            const float2 sef = __half22float2(se2);
            const float2 sgf = __half22float2(sg2);
            const float2 ief = __half22float2(*(__half2*)&ieq[c]);
            const float2 igf = __half22float2(*(__half2*)&igq[c]);

            // point 0
            {
                float ee = __expf(-sef.x), eg = __expf(-sgf.x);
                float Re = ief.x * ee;
                float Rg = igf.x * eg;
                float Le = __builtin_amdgcn_rcpf(ee);
                float Lg = __builtin_amdgcn_rcpf(eg);
                float dr = Re - Rg, dl = Le - Lg;
                acc += dr * dr + dl * dl;
            }
            // point 1
            {
                float ee = __expf(-sef.y), eg = __expf(-sgf.y);
                float Re = ief.y * ee;
                float Rg = igf.y * eg;
                float Le = __builtin_amdgcn_rcpf(ee);
                float Lg = __builtin_amdgcn_rcpf(eg);
                float dr = Re - Rg, dl = Le - Lg;
                acc += dr * dr + dl * dl;
            }
        }
    }
#undef LOADRAW
#undef CBLUR
    return acc;
}

__global__ __launch_bounds__(256)
void k_cn_loss(const ushort* __restrict__ wsS, const ushort* __restrict__ wsI,
               float* __restrict__ out, Taps tp, CMat cm)
{
    const int tid  = threadIdx.x;
    const int half = blockIdx.x >> 9;            // 0: n=0..7, 1: n=8..15
    const int P    = (blockIdx.x & 511) * 256 + tid;   // pair index
    const int hw0  = P * 2;                      // first ushort slot (even)
    const int off  = (hw0 >> 6) * (96 * 64) + (hw0 & 63);
    const ushort* sbase = wsS + off;
    const ushort* ibase = wsI + off;
    // E plane q: uint at +q*64; G plane q: +(48+q)*64

    __half2 k2[9], cw[3][3];
#pragma unroll
    for (int t = 0; t < 9; ++t) k2[t] = __float2half2_rn(tp.k[t]);
#pragma unroll
    for (int i = 0; i < 3; ++i)
#pragma unroll
        for (int j = 0; j < 3; ++j) cw[i][j] = __float2half2_rn(cm.w[i][j]);

    const float acc = (half == 0) ? cn_half<0>(sbase, ibase, k2, cw)
                                  : cn_half<1>(sbase, ibase, k2, cw);

    __shared__ float red[256];
    red[tid] = acc;
    __syncthreads();
#pragma unroll
    for (int s = 128; s > 0; s >>= 1) {
        if (tid < s) red[tid] += red[tid + s];
        __syncthreads();
    }
    if (tid == 0) atomicAdd(out, red[0] * (1.0f / (float)NEL));
}

extern "C" void kernel_launch(void* const* d_in, const int* in_sizes, int n_in,
                              void* d_out, int out_size, void* d_ws, size_t ws_size,
                              hipStream_t stream) {
    const float* Ie = (const float*)d_in[0];
    const float* Ig = (const float*)d_in[1];

    // Gaussian taps: sigma=1, radius=int(4*1+0.5)=4, double-precision normalize
    Taps tp;
    {
        double kk[9], s = 0.0;
        for (int i = 0; i < 9; ++i) { double x = (double)(i - 4); kk[i] = exp(-0.5 * x * x); s += kk[i]; }
        for (int i = 0; i < 9; ++i) tp.k[i] = (float)(kk[i] / s);
    }

    // C-axis (size 3) 9-tap symmetric blur collapsed to a 3x3 matrix
    CMat cm;
    {
        for (int c = 0; c < 3; ++c) {
            cm.w[c][0] = cm.w[c][1] = cm.w[c][2] = 0.f;
            for (int t = 0; t < 9; ++t) {
                int m = c - 4 + t;
                int mm = ((m % 6) + 6) % 6;          // symmetric reflect, period 6
                if (mm > 2) mm = 5 - mm;
                cm.w[c][mm] += tp.k[t];
            }
        }
    }

    ushort* wsS = (ushort*)d_ws;                 // fp16 blurred logs, 50.3 MB
    ushort* wsI = wsS + 2 * (size_t)NEL;         // fp16 (I+eps), 50.3 MB

    dim3 g1(64, 96);
    k_blur_hw<<<g1, 64, 0, stream>>>(Ie, Ig, wsS, wsI, (float*)d_out, tp);
    k_cn_loss<<<1024, 256, 0, stream>>>(wsS, wsI, (float*)d_out, tp, cm);
}

// Round 6
// 161.899 us; speedup vs baseline: 1.0640x; 1.0640x over previous
//
#include <hip/hip_runtime.h>
#include <hip/hip_fp16.h>
#include <cmath>

// Problem constants: (N,C,H,W) = (16,3,512,512), fp32
#define PLANE (512*512)          // 262144
#define NPLANES 48               // N*C
#define NEL (48*PLANE)           // 12582912

struct Taps { float k[9]; };
struct CMat { float w[3][3]; };   // C-axis 9-tap blur collapsed to 3x3 matrix

// ws layout (all fp16, TILED):
//   ushort index(p, h, w-slot) = ((h*8 + tile)*96 + p)*64 + slot
// Each lane owns 8 cols (col=8l..8l+7) stored as 4 uints pairing
// (col+i, col+i+4) in (lo,hi) halves. wsS and wsI use the SAME pairing and
// k_cn_loss is pairing-agnostic (order-independent mean; C/N blurs act
// per-point across planes).
//   wsS[0 .. 2*NEL)   : HW-blurred log, planes 0..47 = image E, 48..95 = G
//   wsI[0 .. 2*NEL)   : (I + 1e-6) values, same plane order

#define FOLD(r) ((r) < 0 ? (-1 - (r)) : ((r) > 511 ? (1023 - (r)) : (r)))

// ---------------------------------------------------------------------------
// Kernel 1: fused log + W-blur + H-blur + I-fp16 staging.
// ONE wave per (16-row strip x FULL 512-col row) of one plane: 8 cols/lane,
// no interior halo, no barriers. Depth-3 global-load pipeline AND depth-1
// SHUFFLE pipeline: row j+1's logs + 8 ds_bpermute are ISSUED before row j's
// W/H-blur (72 pk-fma), so the ~120-cyc DS latency hides under VALU work
// instead of stalling every iteration (R4's diagnosed bubble).
// grid (32, 96), block 64 -> 3072 waves = 12/CU, amp 24/16 = 1.5.
// Block (0,0) zeroes the loss accumulator (replaces memset dispatch).
// ---------------------------------------------------------------------------
__global__ __launch_bounds__(64)
void k_blur_hw(const float* __restrict__ inE, const float* __restrict__ inG,
               ushort* __restrict__ wsS, ushort* __restrict__ wsI,
               float* __restrict__ out, Taps tp)
{
    const int l  = threadIdx.x;               // 0..63 -> cols 8l..8l+7
    const int r0 = blockIdx.x * 16;           // 32 rowgroups
    const int z  = blockIdx.y;                // plane 0..95
    if (blockIdx.x == 0 && blockIdx.y == 0 && l == 0) *out = 0.f;
    const float* __restrict__ src = (z < NPLANES) ? (inE + z * PLANE)
                                                  : (inG + (z - NPLANES) * PLANE);
    const int col  = 8 * l;
    const int tile = l >> 3;                  // w-tile 0..7
    const int sh   = (l & 7) * 8;             // ushort offset inside tile block

    __half2 kh[9];
#pragma unroll
    for (int t = 0; t < 9; ++t) kh[t] = __float2half2_rn(tp.k[t]);

    uint ring[12][4];                         // W-blurred rows, (i,i+4) pairs

    // depth-3 load pipeline over rows r0-4+j
    float4 pA[3], pB[3];
#pragma unroll
    for (int s = 0; s < 3; ++s) {
        const int row = FOLD(r0 - 4 + s);
        pA[s] = *(const float4*)(src + row * 512 + col);
        pB[s] = *(const float4*)(src + row * 512 + col + 4);
    }

    // helper lambdas (inlined): log-pack and window assembly
    auto logpack = [&](const float4& a, const float4& b, uint c[4]) {
        __half2 h0 = __floats2half2_rn(__logf(a.x + 1e-6f), __logf(b.x + 1e-6f));
        __half2 h1 = __floats2half2_rn(__logf(a.y + 1e-6f), __logf(b.y + 1e-6f));
        __half2 h2 = __floats2half2_rn(__logf(a.z + 1e-6f), __logf(b.z + 1e-6f));
        __half2 h3 = __floats2half2_rn(__logf(a.w + 1e-6f), __logf(b.w + 1e-6f));
        c[0] = *(uint*)&h0; c[1] = *(uint*)&h1;
        c[2] = *(uint*)&h2; c[3] = *(uint*)&h3;
    };
    auto assemble = [&](const uint c[4], const uint up[4], const uint dn[4],
                        uint wpk[12]) {
#pragma unroll
        for (int i = 0; i < 4; ++i) {
            wpk[i]     = (up[i] >> 16) | (c[i] << 16);   // (up.hi, own.lo)
            wpk[4 + i] = c[i];
            wpk[8 + i] = (c[i] >> 16) | (dn[i] << 16);   // (own.hi, down.lo)
        }
        if (l == 0) {                     // reflect cols -4..-1 -> 3..0
#pragma unroll
            for (int x = 0; x < 4; ++x)
                wpk[x] = (c[3 - x] & 0xffffu) | (c[x] << 16);
        }
        if (l == 63) {                    // reflect cols 512..515 -> 511..508
            wpk[8]  = (c[0] >> 16) | (c[3] & 0xffff0000u);
            wpk[9]  = (c[1] >> 16) | (c[2] & 0xffff0000u);
            wpk[10] = (c[2] >> 16) | (c[1] & 0xffff0000u);
            wpk[11] = (c[3] >> 16) | (c[0] & 0xffff0000u);
        }
    };

    // prologue: build windows for row j=0 (floats in pA[0]/pB[0])
    uint wpk[12];
    {
        uint c[4], up[4], dn[4];
        logpack(pA[0], pB[0], c);
#pragma unroll
        for (int i = 0; i < 4; ++i) {
            up[i] = (uint)__shfl_up((int)c[i], 1);
            dn[i] = (uint)__shfl_down((int)c[i], 1);
        }
        assemble(c, up, dn, wpk);
    }

    for (int jb = 0; jb < 24; jb += 12) {
#pragma unroll
        for (int u = 0; u < 12; ++u) {
            const int j = jb + u;             // input row r0-4+j

            const float4 a = pA[0], b = pB[0];
            pA[0] = pA[1]; pA[1] = pA[2];
            pB[0] = pB[1]; pB[1] = pB[2];
            if (j + 3 < 24) {                 // load row j+3 (3-iter slack)
                const int row = FOLD(r0 - 1 + j);
                pA[2] = *(const float4*)(src + row * 512 + col);
                pB[2] = *(const float4*)(src + row * 512 + col + 4);
            }

            // stage (I+eps) as fp16 pairs for the 16 center rows (row j)
            if (j >= 4 && j < 20) {
                const int ri = r0 + j - 4;
                __half2 i0 = __floats2half2_rn(a.x + 1e-6f, b.x + 1e-6f);
                __half2 i1 = __floats2half2_rn(a.y + 1e-6f, b.y + 1e-6f);
                __half2 i2 = __floats2half2_rn(a.z + 1e-6f, b.z + 1e-6f);
                __half2 i3 = __floats2half2_rn(a.w + 1e-6f, b.w + 1e-6f);
                ushort* dpI = wsI + (((ri * 8 + tile) * 96) + z) * 64 + sh;
                *(uint4*)dpI = make_uint4(*(uint*)&i0, *(uint*)&i1,
                                          *(uint*)&i2, *(uint*)&i3);
            }

            // ISSUE next row's logs + shuffles (row j+1 floats now in pA[0])
            uint cN[4], upN[4], dnN[4];
            const bool have_next = (j + 1 < 24);
            if (have_next) {
                logpack(pA[0], pB[0], cN);
#pragma unroll
                for (int i = 0; i < 4; ++i) {
                    upN[i] = (uint)__shfl_up((int)cN[i], 1);
                    dnN[i] = (uint)__shfl_down((int)cN[i], 1);
                }
            }

            // CONSUME row j's windows: W-blur (packed fp16) -> ring slot u
#pragma unroll
            for (int i = 0; i < 4; ++i) {
                __half2 acc = __hmul2(kh[0], *(__half2*)&wpk[i]);
#pragma unroll
                for (int t = 1; t < 9; ++t)
                    acc = __hfma2(kh[t], *(__half2*)&wpk[i + t], acc);
                ring[u][i] = *(uint*)&acc;
            }

            // H-blur + store once 9 rows live (output row r0+j-8)
            if (j >= 8) {
                __half2 s0, s1, s2, s3;
                {
                    const int sl = (u + 4) % 12;          // slot of row j-8
                    s0 = __hmul2(kh[0], *(__half2*)&ring[sl][0]);
                    s1 = __hmul2(kh[0], *(__half2*)&ring[sl][1]);
                    s2 = __hmul2(kh[0], *(__half2*)&ring[sl][2]);
                    s3 = __hmul2(kh[0], *(__half2*)&ring[sl][3]);
                }
#pragma unroll
                for (int t = 1; t < 9; ++t) {
                    const int sl = (u + 4 + t) % 12;      // compile-time
                    s0 = __hfma2(kh[t], *(__half2*)&ring[sl][0], s0);
                    s1 = __hfma2(kh[t], *(__half2*)&ring[sl][1], s1);
                    s2 = __hfma2(kh[t], *(__half2*)&ring[sl][2], s2);
                    s3 = __hfma2(kh[t], *(__half2*)&ring[sl][3], s3);
                }
                const int ro = r0 + j - 8;
                ushort* dpS = wsS + (((ro * 8 + tile) * 96) + z) * 64 + sh;
                *(uint4*)dpS = make_uint4(*(uint*)&s0, *(uint*)&s1,
                                          *(uint*)&s2, *(uint*)&s3);
            }

            // assemble row j+1's windows (ds_bpermute wait lands here, after
            // 72 pk-fma of blur work)
            if (have_next) assemble(cN, upN, dnN, wpk);
        }
    }
}

// ---------------------------------------------------------------------------
// Kernel 2: C-blur + N-blur + loss. TWO (h,w) points per thread (one uint);
// ALL loads from the warm fp16 tiled ws (S and I+eps). Packed-half2 ring math.
// grid (512), block (256). (round-0/round-4 verified version, unchanged)
// ---------------------------------------------------------------------------
__global__ __launch_bounds__(256)
void k_cn_loss(const ushort* __restrict__ wsS, const ushort* __restrict__ wsI,
               float* __restrict__ out, Taps tp, CMat cm)
{
    const int tid = threadIdx.x;
    const int P   = blockIdx.x * 256 + tid;      // pair index
    const int hw0 = P * 2;                       // first slot (even)
    const int off = (hw0 >> 6) * (96 * 64) + (hw0 & 63);
    const ushort* sbase = wsS + off;
    const ushort* ibase = wsI + off;
    // E plane q: uint at +q*64; G plane q: +(48+q)*64

    __half2 k2[9], cw[3][3];
#pragma unroll
    for (int t = 0; t < 9; ++t) k2[t] = __float2half2_rn(tp.k[t]);
#pragma unroll
    for (int i = 0; i < 3; ++i)
#pragma unroll
        for (int j = 0; j < 3; ++j) cw[i][j] = __float2half2_rn(cm.w[i][j]);

    __half2 re[9][3];   // ring of C-blurred smoothed-log(E), slot = m % 9
    __half2 rg[9][3];

#define LOADRAW(m, uE, uG)                                                     \
    uE[0] = *(const uint*)(sbase + ((m) * 3 + 0) * 64);                        \
    uE[1] = *(const uint*)(sbase + ((m) * 3 + 1) * 64);                        \
    uE[2] = *(const uint*)(sbase + ((m) * 3 + 2) * 64);                        \
    uG[0] = *(const uint*)(sbase + (48 + (m) * 3 + 0) * 64);                   \
    uG[1] = *(const uint*)(sbase + (48 + (m) * 3 + 1) * 64);                   \
    uG[2] = *(const uint*)(sbase + (48 + (m) * 3 + 2) * 64);

#define CBLUR(u, dst)                                                          \
    {                                                                          \
        __half2 v0 = *(__half2*)&u[0];                                         \
        __half2 v1 = *(__half2*)&u[1];                                         \
        __half2 v2 = *(__half2*)&u[2];                                         \
        dst[0] = __hfma2(cw[0][0], v0, __hfma2(cw[0][1], v1, __hmul2(cw[0][2], v2))); \
        dst[1] = __hfma2(cw[1][0], v0, __hfma2(cw[1][1], v1, __hmul2(cw[1][2], v2))); \
        dst[2] = __hfma2(cw[2][0], v0, __hfma2(cw[2][1], v1, __hmul2(cw[2][2], v2))); \
    }

#pragma unroll
    for (int m = 0; m < 4; ++m) {
        uint uE[3], uG[3];
        LOADRAW(m, uE, uG);
        CBLUR(uE, re[m]); CBLUR(uG, rg[m]);
    }
    uint nuE[3], nuG[3];
    LOADRAW(4, nuE, nuG);
    uint ieq[3], igq[3];                         // packed (I+eps) pairs
#pragma unroll
    for (int c = 0; c < 3; ++c) {
        ieq[c] = *(const uint*)(ibase + c * 64);
        igq[c] = *(const uint*)(ibase + (48 + c) * 64);
    }

    float acc = 0.f;
#pragma unroll
    for (int n = 0; n < 16; ++n) {
        uint nie[3], nig[3];
        if (n + 1 < 16) {
#pragma unroll
            for (int c = 0; c < 3; ++c) {
                nie[c] = *(const uint*)(ibase + (((n + 1) * 3 + c)) * 64);
                nig[c] = *(const uint*)(ibase + ((48 + (n + 1) * 3 + c)) * 64);
            }
        }
        const int mnew = n + 4;
        if (mnew < 16) {
            CBLUR(nuE, re[mnew % 9]); CBLUR(nuG, rg[mnew % 9]);
            if (mnew + 1 < 16) { LOADRAW(mnew + 1, nuE, nuG); }
        }
#pragma unroll
        for (int c = 0; c < 3; ++c) {
            __half2 se2 = __float2half2_rn(0.f), sg2 = se2;
#pragma unroll
            for (int t = 0; t < 9; ++t) {
                int m = n - 4 + t;
                m = (m < 0) ? (-1 - m) : ((m > 15) ? (31 - m) : m);  // compile-time
                se2 = __hfma2(k2[t], re[m % 9][c], se2);
                sg2 = __hfma2(k2[t], rg[m % 9][c], sg2);
            }
            const float2 sef = __half22float2(se2);
            const float2 sgf = __half22float2(sg2);
            const float2 ief = __half22float2(*(__half2*)&ieq[c]);
            const float2 igf = __half22float2(*(__half2*)&igq[c]);

            // point 0
            {
                float ee = __expf(-sef.x), eg = __expf(-sgf.x);
                float Re = ief.x * ee;
                float Rg = igf.x * eg;
                float Le = __builtin_amdgcn_rcpf(ee);
                float Lg = __builtin_amdgcn_rcpf(eg);
                float dr = Re - Rg, dl = Le - Lg;
                acc += dr * dr + dl * dl;
            }
            // point 1
            {
                float ee = __expf(-sef.y), eg = __expf(-sgf.y);
                float Re = ief.y * ee;
                float Rg = igf.y * eg;
                float Le = __builtin_amdgcn_rcpf(ee);
                float Lg = __builtin_amdgcn_rcpf(eg);
                float dr = Re - Rg, dl = Le - Lg;
                acc += dr * dr + dl * dl;
            }
        }
        if (n + 1 < 16) {
#pragma unroll
            for (int c = 0; c < 3; ++c) { ieq[c] = nie[c]; igq[c] = nig[c]; }
        }
    }
#undef LOADRAW
#undef CBLUR

    __shared__ float red[256];
    red[tid] = acc;
    __syncthreads();
#pragma unroll
    for (int s = 128; s > 0; s >>= 1) {
        if (tid < s) red[tid] += red[tid + s];
        __syncthreads();
    }
    if (tid == 0) atomicAdd(out, red[0] * (1.0f / (float)NEL));
}

extern "C" void kernel_launch(void* const* d_in, const int* in_sizes, int n_in,
                              void* d_out, int out_size, void* d_ws, size_t ws_size,
                              hipStream_t stream) {
    const float* Ie = (const float*)d_in[0];
    const float* Ig = (const float*)d_in[1];

    // Gaussian taps: sigma=1, radius=int(4*1+0.5)=4, double-precision normalize
    Taps tp;
    {
        double kk[9], s = 0.0;
        for (int i = 0; i < 9; ++i) { double x = (double)(i - 4); kk[i] = exp(-0.5 * x * x); s += kk[i]; }
        for (int i = 0; i < 9; ++i) tp.k[i] = (float)(kk[i] / s);
    }

    // C-axis (size 3) 9-tap symmetric blur collapsed to a 3x3 matrix
    CMat cm;
    {
        for (int c = 0; c < 3; ++c) {
            cm.w[c][0] = cm.w[c][1] = cm.w[c][2] = 0.f;
            for (int t = 0; t < 9; ++t) {
                int m = c - 4 + t;
                int mm = ((m % 6) + 6) % 6;          // symmetric reflect, period 6
                if (mm > 2) mm = 5 - mm;
                cm.w[c][mm] += tp.k[t];
            }
        }
    }

    ushort* wsS = (ushort*)d_ws;                 // fp16 blurred logs, 50.3 MB
    ushort* wsI = wsS + 2 * (size_t)NEL;         // fp16 (I+eps), 50.3 MB

    dim3 g1(32, 96);
    k_blur_hw<<<g1, 64, 0, stream>>>(Ie, Ig, wsS, wsI, (float*)d_out, tp);
    k_cn_loss<<<512, 256, 0, stream>>>(wsS, wsI, (float*)d_out, tp, cm);
}

// Round 7
// 159.076 us; speedup vs baseline: 1.0829x; 1.0177x over previous
//
#include <hip/hip_runtime.h>
#include <hip/hip_fp16.h>
#include <cmath>

// Problem constants: (N,C,H,W) = (16,3,512,512), fp32
#define PLANE (512*512)          // 262144
#define NPLANES 48               // N*C
#define NEL (48*PLANE)           // 12582912

struct Taps { float k[9]; };
struct CMat { float w[3][3]; };   // C-axis 9-tap blur collapsed to 3x3 matrix

// ws layout (fp16, TILED):
//   ushort index(p, h, slot) = ((h*8 + tile)*96 + p)*64 + slot
// Lane l owns cols 8l..8l+7; uint q at slot (l&7)*8 + 2q holds the ADJACENT
// pair (col+2q, col+2q+1). k_cn_loss's partner (I+eps) values are then one
// coalesced float2 from the ORIGINAL fp32 input (L3-resident), so I is not
// staged at all (saves 50.3 MB of HBM writes).
//   wsS[0 .. 2*NEL) : HW-blurred log, planes 0..47 = image E, 48..95 = G

#define FOLD(r) ((r) < 0 ? (-1 - (r)) : ((r) > 511 ? (1023 - (r)) : (r)))

__device__ __forceinline__ uint swap16(uint x) { return (x >> 16) | (x << 16); }
// pack(x) for odd x: lo = hi(pack(x-1)), hi = lo(pack(x+1))
__device__ __forceinline__ uint align16(uint hiSrc, uint loSrc) {
    return (loSrc >> 16) | (hiSrc << 16);
}

// ---------------------------------------------------------------------------
// Kernel 1: fused log + W-blur + H-blur (NO I staging).
// ONE wave per (16-row strip x FULL 512-col row) of one plane: 8 cols/lane,
// no barriers. DEPTH-6 indexed-circular global prefetch (~1000 cyc slack >
// HBM latency; K1 was stuck at ~3 TB/s effective = concurrency-limited).
// Adjacent-pair fp16 packing: 4 cvt_pk + 4 shuffles + 7 alignbit per row;
// per-element tap chains bit-identical to the R4/R6-verified datapath.
// grid (32, 96), block 64 -> 3072 waves = 12/CU, amp 24/16 = 1.5.
// Block (0,0) zeroes the loss accumulator (replaces memset dispatch).
// ---------------------------------------------------------------------------
__global__ __launch_bounds__(64, 3)
void k_blur_hw(const float* __restrict__ inE, const float* __restrict__ inG,
               ushort* __restrict__ wsS, float* __restrict__ out, Taps tp)
{
    const int l  = threadIdx.x;               // 0..63 -> cols 8l..8l+7
    const int r0 = blockIdx.x * 16;           // 32 rowgroups
    const int z  = blockIdx.y;                // plane 0..95
    if (blockIdx.x == 0 && blockIdx.y == 0 && l == 0) *out = 0.f;
    const float* __restrict__ src = (z < NPLANES) ? (inE + z * PLANE)
                                                  : (inG + (z - NPLANES) * PLANE);
    const int col  = 8 * l;
    const int tile = l >> 3;                  // w-tile 0..7
    const int sh   = (l & 7) * 8;             // ushort offset inside tile block

    __half2 kh[9];
#pragma unroll
    for (int t = 0; t < 9; ++t) kh[t] = __float2half2_rn(tp.k[t]);

    uint ring[12][4];                         // W-blurred rows, adjacent pairs

    // depth-6 indexed circular prefetch over rows r0-4+j
    float4 pA[6], pB[6];
#pragma unroll
    for (int s = 0; s < 6; ++s) {
        const int row = FOLD(r0 - 4 + s);
        pA[s] = *(const float4*)(src + row * 512 + col);
        pB[s] = *(const float4*)(src + row * 512 + col + 4);
    }

    for (int jb = 0; jb < 24; jb += 12) {
#pragma unroll
        for (int u = 0; u < 12; ++u) {
            const int j   = jb + u;           // input row r0-4+j
            const int sl6 = u % 6;            // compile-time (12 % 6 == 0)

            const float4 a = pA[sl6], b = pB[sl6];
            if (j + 6 < 24) {                 // refill slot for row j+6
                const int row = FOLD(r0 + 2 + j);
                pA[sl6] = *(const float4*)(src + row * 512 + col);
                pB[sl6] = *(const float4*)(src + row * 512 + col + 4);
            }

            // fp32 log -> adjacent-pair fp16 packs
            const float e0 = __logf(a.x + 1e-6f), e1 = __logf(a.y + 1e-6f);
            const float e2 = __logf(a.z + 1e-6f), e3 = __logf(a.w + 1e-6f);
            const float e4 = __logf(b.x + 1e-6f), e5 = __logf(b.y + 1e-6f);
            const float e6 = __logf(b.z + 1e-6f), e7 = __logf(b.w + 1e-6f);
            __half2 h01 = __floats2half2_rn(e0, e1);
            __half2 h23 = __floats2half2_rn(e2, e3);
            __half2 h45 = __floats2half2_rn(e4, e5);
            __half2 h67 = __floats2half2_rn(e6, e7);
            const uint P0 = *(uint*)&h01, P2 = *(uint*)&h23;
            const uint P4 = *(uint*)&h45, P6 = *(uint*)&h67;

            // pk[x+4] = (w[col+x], w[col+x+1]), x = -4..10
            uint U4 = (uint)__shfl_up((int)P4, 1);    // (w[col-4], w[col-3])
            uint U6 = (uint)__shfl_up((int)P6, 1);    // (w[col-2], w[col-1])
            uint D0 = (uint)__shfl_down((int)P0, 1);  // (w[col+8], w[col+9])
            uint D2 = (uint)__shfl_down((int)P2, 1);  // (w[col+10], w[col+11])
            if (l == 0)  { U4 = swap16(P2); U6 = swap16(P0); }  // reflect 3,2 / 1,0
            if (l == 63) { D0 = swap16(P6); D2 = swap16(P4); }  // reflect 511,510 / 509,508
            uint pk[15];
            pk[0] = U4; pk[2] = U6; pk[4] = P0; pk[6] = P2;
            pk[8] = P4; pk[10] = P6; pk[12] = D0; pk[14] = D2;
#pragma unroll
            for (int x = 0; x < 7; ++x) pk[2 * x + 1] = align16(pk[2 * x + 2], pk[2 * x]);

            // W-blur: uint q = pair (out[col+2q], out[col+2q+1])
#pragma unroll
            for (int q = 0; q < 4; ++q) {
                __half2 acc = __hmul2(kh[0], *(__half2*)&pk[2 * q]);
#pragma unroll
                for (int t = 1; t < 9; ++t)
                    acc = __hfma2(kh[t], *(__half2*)&pk[2 * q + t], acc);
                ring[u][q] = *(uint*)&acc;
            }

            // H-blur + store once 9 rows live (output row r0+j-8)
            if (j >= 8) {
                __half2 s0, s1, s2, s3;
                {
                    const int sl = (u + 4) % 12;          // slot of row j-8
                    s0 = __hmul2(kh[0], *(__half2*)&ring[sl][0]);
                    s1 = __hmul2(kh[0], *(__half2*)&ring[sl][1]);
                    s2 = __hmul2(kh[0], *(__half2*)&ring[sl][2]);
                    s3 = __hmul2(kh[0], *(__half2*)&ring[sl][3]);
                }
#pragma unroll
                for (int t = 1; t < 9; ++t) {
                    const int sl = (u + 4 + t) % 12;      // compile-time
                    s0 = __hfma2(kh[t], *(__half2*)&ring[sl][0], s0);
                    s1 = __hfma2(kh[t], *(__half2*)&ring[sl][1], s1);
                    s2 = __hfma2(kh[t], *(__half2*)&ring[sl][2], s2);
                    s3 = __hfma2(kh[t], *(__half2*)&ring[sl][3], s3);
                }
                const int ro = r0 + j - 8;
                ushort* dpS = wsS + (((ro * 8 + tile) * 96) + z) * 64 + sh;
                *(uint4*)dpS = make_uint4(*(uint*)&s0, *(uint*)&s1,
                                          *(uint*)&s2, *(uint*)&s3);
            }
        }
    }
}

// ---------------------------------------------------------------------------
// Kernel 2: C-blur + N-blur + loss. TWO adjacent (h,w) points per thread;
// S from warm fp16 tiled ws, I+eps recomputed from the ORIGINAL fp32 inputs
// (one coalesced float2 per plane, L3-resident). Structure unchanged from
// the verified round-0 kernel. grid (512), block (256).
// ---------------------------------------------------------------------------
__global__ __launch_bounds__(256)
void k_cn_loss(const ushort* __restrict__ wsS,
               const float* __restrict__ inE, const float* __restrict__ inG,
               float* __restrict__ out, Taps tp, CMat cm)
{
    const int tid = threadIdx.x;
    const int P   = blockIdx.x * 256 + tid;      // pair index
    const int hw0 = P * 2;                       // first ushort slot (even)
    const int hb  = hw0 >> 6;                    // h*8 + tile
    const ushort* sbase = wsS + hb * (96 * 64) + (hw0 & 63);
    // E plane q: uint at +q*64; G plane q: +(48+q)*64
    const int h     = hb >> 3;
    const int tile  = hb & 7;
    const int mu    = (hw0 & 63) >> 1;           // uint index in tile block
    const int basew = tile * 64 + ((mu >> 2) << 3) + ((mu & 3) << 1);
    const float* __restrict__ ibE = inE + (size_t)h * 512 + basew;
    const float* __restrict__ ibG = inG + (size_t)h * 512 + basew;
    // plane q at + q*PLANE (float2 covers the pair (basew, basew+1))

    __half2 k2[9], cw[3][3];
#pragma unroll
    for (int t = 0; t < 9; ++t) k2[t] = __float2half2_rn(tp.k[t]);
#pragma unroll
    for (int i = 0; i < 3; ++i)
#pragma unroll
        for (int j = 0; j < 3; ++j) cw[i][j] = __float2half2_rn(cm.w[i][j]);

    __half2 re[9][3];   // ring of C-blurred smoothed-log(E), slot = m % 9
    __half2 rg[9][3];

#define LOADRAW(m, uE, uG)                                                     \
    uE[0] = *(const uint*)(sbase + ((m) * 3 + 0) * 64);                        \
    uE[1] = *(const uint*)(sbase + ((m) * 3 + 1) * 64);                        \
    uE[2] = *(const uint*)(sbase + ((m) * 3 + 2) * 64);                        \
    uG[0] = *(const uint*)(sbase + (48 + (m) * 3 + 0) * 64);                   \
    uG[1] = *(const uint*)(sbase + (48 + (m) * 3 + 1) * 64);                   \
    uG[2] = *(const uint*)(sbase + (48 + (m) * 3 + 2) * 64);

#define CBLUR(u, dst)                                                          \
    {                                                                          \
        __half2 v0 = *(__half2*)&u[0];                                         \
        __half2 v1 = *(__half2*)&u[1];                                         \
        __half2 v2 = *(__half2*)&u[2];                                         \
        dst[0] = __hfma2(cw[0][0], v0, __hfma2(cw[0][1], v1, __hmul2(cw[0][2], v2))); \
        dst[1] = __hfma2(cw[1][0], v0, __hfma2(cw[1][1], v1, __hmul2(cw[1][2], v2))); \
        dst[2] = __hfma2(cw[2][0], v0, __hfma2(cw[2][1], v1, __hmul2(cw[2][2], v2))); \
    }

#pragma unroll
    for (int m = 0; m < 4; ++m) {
        uint uE[3], uG[3];
        LOADRAW(m, uE, uG);
        CBLUR(uE, re[m]); CBLUR(uG, rg[m]);
    }
    uint nuE[3], nuG[3];
    LOADRAW(4, nuE, nuG);
    float2 fe[3], fg[3];                         // fp32 I pairs
#pragma unroll
    for (int c = 0; c < 3; ++c) {
        fe[c] = *(const float2*)(ibE + (size_t)c * PLANE);
        fg[c] = *(const float2*)(ibG + (size_t)c * PLANE);
    }

    float acc = 0.f;
#pragma unroll
    for (int n = 0; n < 16; ++n) {
        float2 nfe[3], nfg[3];
        if (n + 1 < 16) {
#pragma unroll
            for (int c = 0; c < 3; ++c) {
                nfe[c] = *(const float2*)(ibE + (size_t)((n + 1) * 3 + c) * PLANE);
                nfg[c] = *(const float2*)(ibG + (size_t)((n + 1) * 3 + c) * PLANE);
            }
        }
        const int mnew = n + 4;
        if (mnew < 16) {
            CBLUR(nuE, re[mnew % 9]); CBLUR(nuG, rg[mnew % 9]);
            if (mnew + 1 < 16) { LOADRAW(mnew + 1, nuE, nuG); }
        }
#pragma unroll
        for (int c = 0; c < 3; ++c) {
            __half2 se2 = __float2half2_rn(0.f), sg2 = se2;
#pragma unroll
            for (int t = 0; t < 9; ++t) {
                int m = n - 4 + t;
                m = (m < 0) ? (-1 - m) : ((m > 15) ? (31 - m) : m);  // compile-time
                se2 = __hfma2(k2[t], re[m % 9][c], se2);
                sg2 = __hfma2(k2[t], rg[m % 9][c], sg2);
            }
            const float2 sef = __half22float2(se2);
            const float2 sgf = __half22float2(sg2);

            // point 0
            {
                float ee = __expf(-sef.x), eg = __expf(-sgf.x);
                float Re = (fe[c].x + 1e-6f) * ee;
                float Rg = (fg[c].x + 1e-6f) * eg;
                float Le = __builtin_amdgcn_rcpf(ee);
                float Lg = __builtin_amdgcn_rcpf(eg);
                float dr = Re - Rg, dl = Le - Lg;
                acc += dr * dr + dl * dl;
            }
            // point 1
            {
                float ee = __expf(-sef.y), eg = __expf(-sgf.y);
                float Re = (fe[c].y + 1e-6f) * ee;
                float Rg = (fg[c].y + 1e-6f) * eg;
                float Le = __builtin_amdgcn_rcpf(ee);
                float Lg = __builtin_amdgcn_rcpf(eg);
                float dr = Re - Rg, dl = Le - Lg;
                acc += dr * dr + dl * dl;
            }
        }
        if (n + 1 < 16) {
#pragma unroll
            for (int c = 0; c < 3; ++c) { fe[c] = nfe[c]; fg[c] = nfg[c]; }
        }
    }
#undef LOADRAW
#undef CBLUR

    __shared__ float red[256];
    red[tid] = acc;
    __syncthreads();
#pragma unroll
    for (int s = 128; s > 0; s >>= 1) {
        if (tid < s) red[tid] += red[tid + s];
        __syncthreads();
    }
    if (tid == 0) atomicAdd(out, red[0] * (1.0f / (float)NEL));
}

extern "C" void kernel_launch(void* const* d_in, const int* in_sizes, int n_in,
                              void* d_out, int out_size, void* d_ws, size_t ws_size,
                              hipStream_t stream) {
    const float* Ie = (const float*)d_in[0];
    const float* Ig = (const float*)d_in[1];

    // Gaussian taps: sigma=1, radius=int(4*1+0.5)=4, double-precision normalize
    Taps tp;
    {
        double kk[9], s = 0.0;
        for (int i = 0; i < 9; ++i) { double x = (double)(i - 4); kk[i] = exp(-0.5 * x * x); s += kk[i]; }
        for (int i = 0; i < 9; ++i) tp.k[i] = (float)(kk[i] / s);
    }

    // C-axis (size 3) 9-tap symmetric blur collapsed to a 3x3 matrix
    CMat cm;
    {
        for (int c = 0; c < 3; ++c) {
            cm.w[c][0] = cm.w[c][1] = cm.w[c][2] = 0.f;
            for (int t = 0; t < 9; ++t) {
                int m = c - 4 + t;
                int mm = ((m % 6) + 6) % 6;          // symmetric reflect, period 6
                if (mm > 2) mm = 5 - mm;
                cm.w[c][mm] += tp.k[t];
            }
        }
    }

    ushort* wsS = (ushort*)d_ws;                 // fp16 blurred logs, 50.3 MB

    dim3 g1(32, 96);
    k_blur_hw<<<g1, 64, 0, stream>>>(Ie, Ig, wsS, (float*)d_out, tp);
    k_cn_loss<<<512, 256, 0, stream>>>(wsS, Ie, Ig, (float*)d_out, tp, cm);
}